// Round 3
// baseline (1113.774 us; speedup 1.0000x reference)
//
#include <hip/hip_runtime.h>

#define C_CH   64
#define H_IN   200
#define W_IN   320
#define H_OUT  48
#define W_OUT  320
#define N_BOX  256

typedef float float4v __attribute__((ext_vector_type(4), aligned(16)));

typedef __attribute__((address_space(3))) void       lds_vp;
typedef __attribute__((address_space(1))) const void gbl_vp;

__device__ __forceinline__ void glds16(const float* g, float* l) {
    __builtin_amdgcn_global_load_lds((gbl_vp*)g, (lds_vp*)l, 16, 0, 0);
}

// One block per (box, channel), 320 threads, single barrier.
//
// Phase 1: stage ONLY the bbox sub-rectangle into LDS via async global->LDS:
//   nur = min(h,48) unique rows x K4 (<=80) float4-columns. Avg traffic
//   ~16 KB/block vs 61 KB for full-width staging (worst case identical).
//   Rows staged: h<=48 -> y0..y0+h-1 (slot s = r-y0, read slot = i*h/48);
//                h> 48 -> the 48 distinct rows r(i) (slot s = i).
//
// Phase 2: thread t produces 12 float4s (p = t + k*320 -> row i=p/80, group
//   u=p%80): 4 LDS gathers (lane col-stride <= 4 -> <=8-way conflict, ~3x on
//   the LDS pipe, overlapped) packed into one PLAIN global_store_dwordx4 --
//   mirroring the fillBuffer pattern that demonstrably sustains 6.3 TB/s in
//   this harness, vs the 4B/lane nontemporal stores (~2.2 TB/s) used by every
//   previous round (the cross-round invariant).
__global__ __launch_bounds__(320) void roi_crop_kernel(
    const float* __restrict__ x,
    const int*   __restrict__ bboxes,
    const int*   __restrict__ box_img,
    float*       __restrict__ out)
{
    __shared__ __align__(16) float tile[H_OUT * 80 * 4];   // 61440 B worst case

    const int box = blockIdx.x;   // box fastest: same-image boxes co-resident (L2 row reuse)
    const int c   = blockIdx.y;
    const int t   = threadIdx.x;  // 0..319

    const int4 bb = *(const int4*)(bboxes + box * 4);
    int x0 = min(max(bb.x, 0), W_IN - 1);
    int y0 = min(max(bb.y, 0), H_IN - 1);
    int x1 = min(max(bb.z, 0), W_IN - 1);
    int y1 = min(max(bb.w, 0), H_IN - 1);
    x1 = max(x1, x0);
    y1 = max(y1, y0);

    const int h   = y1 - y0 + 1;
    const int w   = x1 - x0 + 1;
    const int img = box_img[box];

    const float* __restrict__ plane_in =
        x + ((size_t)img * C_CH + c) * (H_IN * W_IN);
    float* __restrict__ plane_out =
        out + ((size_t)box * C_CH + c) * (H_OUT * W_OUT);

    const int x0f4 = x0 >> 2;                 // first float4-col staged
    const int K4   = (x1 >> 2) - x0f4 + 1;    // float4s per staged row, <= 80
    const int x0f  = x0f4 << 2;               // first float col staged (16B-aligned)
    const int nur  = (h < H_OUT) ? h : H_OUT; // unique rows staged
    const bool small_h = (h <= H_OUT);

    // ---- Phase 1: async sub-rect staging. Threads t<K4 issue 1 glds per row.
    // glds dest is linear in lane order: byte (s*K4 + t)*16 = wave-uniform
    // base + lane*16 (t = 64*wave + lane). Source 16B-aligned (x0f, row 1280B).
    for (int s = 0; s < nur; ++s) {
        const int rs = small_h ? (y0 + s) : (y0 + (s * h) / H_OUT);
        if (t < K4)
            glds16(plane_in + (size_t)rs * W_IN + x0f + (t << 2),
                   &tile[(s * K4 + t) << 2]);
    }
    __syncthreads();   // drains vmcnt(0) incl. global_load_lds

    // ---- Phase 2: gather 4 cols -> float4 -> plain wide store.
    const int ldrow = K4 << 2;                // floats per staged row
    float4v* __restrict__ out4 = (float4v*)plane_out;
    #pragma unroll
    for (int k = 0; k < 12; ++k) {
        const int p = t + k * 320;            // float4 index 0..3839
        const int i = p / 80;                 // output row
        const int u = p - i * 80;             // float4 within row
        const int s = small_h ? (i * h) / H_OUT : i;
        const int base = s * ldrow - x0f;
        float4v v;
        #pragma unroll
        for (int e = 0; e < 4; ++e) {
            const int ce = x0 + ((4 * u + e) * w) / W_OUT;
            v[e] = tile[base + ce];
        }
        out4[p] = v;                          // 1024 B/wave, coalesced, non-nt
    }
}

extern "C" void kernel_launch(void* const* d_in, const int* in_sizes, int n_in,
                              void* d_out, int out_size, void* d_ws, size_t ws_size,
                              hipStream_t stream) {
    const float* x       = (const float*)d_in[0];
    const int*   bboxes  = (const int*)d_in[1];
    const int*   box_img = (const int*)d_in[2];
    float*       out     = (float*)d_out;

    dim3 grid(N_BOX, C_CH);   // (256, 64) = 16384 blocks
    dim3 block(320);
    roi_crop_kernel<<<grid, block, 0, stream>>>(x, bboxes, box_img, out);
}

// Round 4
// 1093.643 us; speedup vs baseline: 1.0184x; 1.0184x over previous
//
#include <hip/hip_runtime.h>

#define C_CH   64
#define H_IN   200
#define W_IN   320
#define H_OUT  48
#define W_OUT  320
#define N_BOX  256
#define SLICE  12              // output rows per block
#define NSLICE (H_OUT / SLICE) // 4

typedef float float4v __attribute__((ext_vector_type(4), aligned(16)));

// Round-0 structure (the measured-best regime) + two principled deltas:
//
// 1. grid = (channel, box, slice) with CHANNEL FASTEST. Cross-round evidence:
//    rounds 1-3 (box-fastest) all ~470 us kernel-only despite 3x read-traffic
//    and 4x store-width variation; round 0 (channel-fastest) ~408 us. For a
//    983 MB write-dominated kernel, consecutive blocks writing CONTIGUOUS
//    61 KB output regions (round-robin across XCDs) is the locality that
//    matters; reads are L3-served and nearly free either way.
//
// 2. 4 row-slices per (c,box): LDS 61,440 -> 15,360 B. Residency goes from
//    LDS-capped 2 blocks/CU to thread-capped 6 blocks/CU (1920/2048). Six
//    independent blocks interleave stage/barrier/store phases per CU -- the
//    overlap round 2's explicit vmcnt pipeline failed to buy, obtained by
//    block granularity instead of instruction choreography.
//
// Staging stays reg-staged dwordx4 (round 0's proven path: independent loads,
// compiler batches them, one latency round-trip). Stores are 3 dwordx4/thread.
__global__ __launch_bounds__(320) void roi_crop_kernel(
    const float* __restrict__ x,
    const int*   __restrict__ bboxes,
    const int*   __restrict__ box_img,
    float*       __restrict__ out)
{
    __shared__ __align__(16) float tile[SLICE * W_IN];   // 15,360 B

    const int c   = blockIdx.x;           // channel 0..63  (fastest)
    const int box = blockIdx.y;           // box     0..255
    const int i0  = blockIdx.z * SLICE;   // first output row of this slice
    const int t   = threadIdx.x;          // 0..319

    const int4 bb = *(const int4*)(bboxes + box * 4);
    int x0 = min(max(bb.x, 0), W_IN - 1);
    int y0 = min(max(bb.y, 0), H_IN - 1);
    int x1 = min(max(bb.z, 0), W_IN - 1);
    int y1 = min(max(bb.w, 0), H_IN - 1);
    x1 = max(x1, x0);
    y1 = max(y1, y0);

    const int h   = y1 - y0 + 1;
    const int w   = x1 - x0 + 1;
    const int img = box_img[box];

    const float* __restrict__ plane_in =
        x + ((size_t)img * C_CH + c) * (H_IN * W_IN);
    float* __restrict__ plane_out =
        out + ((size_t)box * C_CH + c) * (H_OUT * W_OUT);

    // ---- Phase 1: stage 12 full-width rows. 960 float4s / 320 threads = 3 each.
    float4v v[3];
    #pragma unroll
    for (int k = 0; k < 3; ++k) {
        const int p   = t + k * 320;            // float4 index 0..959
        const int il  = p / 80;                 // local output row 0..11
        const int wrd = p - il * 80;            // float4 within row
        const int r   = y0 + ((i0 + il) * h) / H_OUT;
        v[k] = *(const float4v*)(plane_in + (size_t)r * W_IN + wrd * 4);
    }
    #pragma unroll
    for (int k = 0; k < 3; ++k)
        *(float4v*)&tile[(t + k * 320) * 4] = v[k];
    __syncthreads();

    // ---- Phase 2: gather 4 cols per float4, wide coalesced store.
    float4v* __restrict__ out4 = (float4v*)plane_out;
    #pragma unroll
    for (int k = 0; k < 3; ++k) {
        const int p  = t + k * 320;             // float4 index 0..959
        const int il = p / 80;                  // local output row
        const int u  = p - il * 80;             // float4 within row
        float4v o;
        #pragma unroll
        for (int e = 0; e < 4; ++e) {
            const int ce = x0 + ((4 * u + e) * w) / W_OUT;  // <=8-way LDS conflict worst case
            o[e] = tile[il * W_IN + ce];
        }
        out4[(size_t)(i0 + il) * 80 + u] = o;   // 1024 B/wave, contiguous
    }
}

extern "C" void kernel_launch(void* const* d_in, const int* in_sizes, int n_in,
                              void* d_out, int out_size, void* d_ws, size_t ws_size,
                              hipStream_t stream) {
    const float* x       = (const float*)d_in[0];
    const int*   bboxes  = (const int*)d_in[1];
    const int*   box_img = (const int*)d_in[2];
    float*       out     = (float*)d_out;

    dim3 grid(C_CH, N_BOX, NSLICE);   // (64, 256, 4) = 65536 blocks, channel fastest
    dim3 block(320);
    roi_crop_kernel<<<grid, block, 0, stream>>>(x, bboxes, box_img, out);
}

// Round 5
// 1078.068 us; speedup vs baseline: 1.0331x; 1.0144x over previous
//
#include <hip/hip_runtime.h>

#define C_CH    64
#define H_IN    200
#define W_IN    320
#define H_OUT   48
#define W_OUT   320
#define N_BOX   256
#define ROWS_PP 16                  // rows staged per pass
#define NPASS   (H_OUT / ROWS_PP)   // 3

typedef float float4v __attribute__((ext_vector_type(4), aligned(16)));

// Round-0 (measured-best: ~408 us kernel-only) with EXACTLY ONE structural
// change: the 48-row monolithic LDS tile (61,440 B -> 2 blocks/CU, 10 waves)
// becomes 3 passes of 16 rows (20,480 B -> thread-capped 6 blocks/CU, 30
// waves). Everything else is identical to R0: grid (64,256) channel-fastest,
// 320 threads, reg-staged dwordx4 row loads, conflict-free scalar LDS gather
// (thread t = output col j, lane col-step <= 1), nontemporal dword stores.
// Block count unchanged (16,384) -- avoids R4's 4x per-block overhead.
//
// Free pipeline: each pass's 4 staging loads are issued BEFORE the
// pre-overwrite barrier (issue-early / write-late), so next-pass read
// latency hides under the previous pass's store stream; 6 co-resident
// blocks interleave their barriers.
__global__ __launch_bounds__(320) void roi_crop_kernel(
    const float* __restrict__ x,
    const int*   __restrict__ bboxes,
    const int*   __restrict__ box_img,
    float*       __restrict__ out)
{
    __shared__ __align__(16) float tile[ROWS_PP * W_IN];   // 20,480 B

    const int c   = blockIdx.x;   // channel 0..63 (fastest -> contiguous output regions)
    const int box = blockIdx.y;   // box 0..255
    const int t   = threadIdx.x;  // 0..319

    const int4 bb = *(const int4*)(bboxes + box * 4);
    int x0 = min(max(bb.x, 0), W_IN - 1);
    int y0 = min(max(bb.y, 0), H_IN - 1);
    int x1 = min(max(bb.z, 0), W_IN - 1);
    int y1 = min(max(bb.w, 0), H_IN - 1);
    x1 = max(x1, x0);
    y1 = max(y1, y0);

    const int h   = y1 - y0 + 1;
    const int w   = x1 - x0 + 1;
    const int img = box_img[box];

    const float* __restrict__ plane_in =
        x + ((size_t)img * C_CH + c) * (H_IN * W_IN);
    float* __restrict__ plane_out =
        out + ((size_t)box * C_CH + c) * (H_OUT * W_OUT);

    const int col = x0 + (t * w) / W_OUT;   // lane step <= 1 -> conflict-free

    #pragma unroll
    for (int pass = 0; pass < NPASS; ++pass) {
        const int ibase = pass * ROWS_PP;

        // Stage 16 rows x 320 cols: 1280 float4s / 320 threads = 4 each.
        // Loads issued BEFORE the pre-overwrite barrier (prefetch overlap).
        float4v v[4];
        #pragma unroll
        for (int k = 0; k < 4; ++k) {
            const int p   = t + k * 320;        // float4 index 0..1279
            const int il  = p / 80;             // local row 0..15
            const int wrd = p - il * 80;        // float4 within row
            const int r   = y0 + ((ibase + il) * h) / H_OUT;
            v[k] = *(const float4v*)(plane_in + (size_t)r * W_IN + wrd * 4);
        }

        if (pass) __syncthreads();              // prev pass's readers done
        #pragma unroll
        for (int k = 0; k < 4; ++k)
            *(float4v*)&tile[(t + k * 320) * 4] = v[k];
        __syncthreads();                        // tile resident

        // Gather + contiguous nt store, 16 rows. j = t.
        #pragma unroll
        for (int il = 0; il < ROWS_PP; ++il) {
            const float val = tile[il * W_IN + col];
            __builtin_nontemporal_store(val,
                plane_out + (size_t)(ibase + il) * W_OUT + t);
        }
    }
}

extern "C" void kernel_launch(void* const* d_in, const int* in_sizes, int n_in,
                              void* d_out, int out_size, void* d_ws, size_t ws_size,
                              hipStream_t stream) {
    const float* x       = (const float*)d_in[0];
    const int*   bboxes  = (const int*)d_in[1];
    const int*   box_img = (const int*)d_in[2];
    float*       out     = (float*)d_out;

    dim3 grid(C_CH, N_BOX);   // (64, 256) = 16,384 blocks, channel fastest
    dim3 block(320);
    roi_crop_kernel<<<grid, block, 0, stream>>>(x, bboxes, box_img, out);
}